// Round 8
// baseline (359.773 us; speedup 1.0000x reference)
//
#include <hip/hip_runtime.h>
#include <hip/hip_bf16.h>
#include <math.h>

// Problem constants
#define B_    32
#define N_    1024
#define DIM_  512
#define HEAD_ 8
#define HD_   64        // head dim
#define WSP   32        // sqrt(N)
#define M2    256       // kv spatial positions (16*16)
#define CDIM  1024      // 2*DIM
#define KCONV 4608      // DIM*3*3
#define EPS_  1e-5f
#define SCALE_ 0.044194173824159216f  // DIM^-0.5
#define PW    34        // padded spatial side (32 + 2 halo)

typedef __attribute__((ext_vector_type(8))) short bf16x8;
typedef __attribute__((ext_vector_type(4))) float f32x4_t;
typedef const __attribute__((address_space(1))) void gas_t;   // global addr space
typedef __attribute__((address_space(3))) void las_t;         // LDS addr space

__device__ __forceinline__ ushort f2b(float x) {
  __hip_bfloat16 h = __float2bfloat16(x);
  return *reinterpret_cast<const ushort*>(&h);
}

// ---------------------------------------------------------------------------
// fp32 -> bf16 cast, 4 elems/thread (weights)
// ---------------------------------------------------------------------------
__global__ __launch_bounds__(256) void cast_f32_bf16_kernel(
    const float* __restrict__ in, ushort* __restrict__ out, int n4) {
  int i = blockIdx.x * 256 + threadIdx.x;
  if (i >= n4) return;
  float4 v = reinterpret_cast<const float4*>(in)[i];
  ushort4 o;
  o.x = f2b(v.x); o.y = f2b(v.y); o.z = f2b(v.z); o.w = f2b(v.w);
  reinterpret_cast<ushort4*>(out)[i] = o;
}

// ---------------------------------------------------------------------------
// Zero only the halo border of featsp [b][34][34][512] (16B per thread)
// 32 b x 132 border cells x 64 ushort8-groups = 270336 threads
// ---------------------------------------------------------------------------
__global__ __launch_bounds__(256) void zero_border_kernel(ushort* __restrict__ featsp) {
  int t = blockIdx.x * 256 + threadIdx.x;
  int b = t / 8448, r = t - b * 8448;          // 8448 = 132*64
  int cell = r >> 6, ic8 = (r & 63) * 8;
  int iw, ih;
  if (cell < 34)      { iw = 0;  ih = cell; }
  else if (cell < 68) { iw = 33; ih = cell - 34; }
  else { int e = cell - 68; iw = 1 + (e >> 1); ih = (e & 1) * 33; }
  bf16x8 z = {};
  *reinterpret_cast<bf16x8*>(&featsp[(((size_t)b * PW + iw) * PW + ih) * 512 + ic8]) = z;
}

// ---------------------------------------------------------------------------
// feats f32 [b][n=iw*32+ih][ic] -> zero-padded bf16 [b][iw+1][ih+1][ic]
// ---------------------------------------------------------------------------
__global__ __launch_bounds__(256) void cast_featsp_kernel(
    const float* __restrict__ feats, ushort* __restrict__ featsp) {
  int i = blockIdx.x * 256 + threadIdx.x;       // ushort4 index
  int e = i * 4;
  int b = e >> 19, r = e & 524287;
  int n = r >> 9, ic = r & 511;
  int iw = n >> 5, ih = n & 31;
  float4 v = reinterpret_cast<const float4*>(feats)[i];
  ushort4 o;
  o.x = f2b(v.x); o.y = f2b(v.y); o.z = f2b(v.z); o.w = f2b(v.w);
  size_t dst = (((size_t)b * PW + iw + 1) * PW + ih + 1) * 512 + ic;
  *reinterpret_cast<ushort4*>(&featsp[dst]) = o;
}

// ---------------------------------------------------------------------------
// conv_w [oc][ic*9 + tap] fp32 -> bf16 [oc][tap*512 + ic]
// ---------------------------------------------------------------------------
__global__ __launch_bounds__(256) void permute_convw_kernel(
    const float* __restrict__ in, ushort* __restrict__ out) {
  int oc = blockIdx.y;
  int idx = blockIdx.x * 256 + threadIdx.x;  // [0, 4608)
  int tap = idx >> 9, ic = idx & 511;
  out[(size_t)oc * KCONV + idx] = f2b(in[(size_t)oc * KCONV + ic * 9 + tap]);
}

// ---------------------------------------------------------------------------
// MFMA bf16 GEMM: C[M x N] = A[M x K] * B[N x K]^T
// 128x128 tile, BK=32, 4 waves, LDS double-buffer, global_load_lds(16B),
// 2-phase loop, XCD-chunked swizzle, conflict-free LDS via source-permuted
// chunk swizzle.
// MODE 0: A = plain bf16 buffer            -> C f32
// MODE 1: A = padded-feats center-tap rows -> C bf16   (q-proj)
// MODE 2: A = padded-feats im2col 3x3 s2   -> C f32 + bias (conv)
// ---------------------------------------------------------------------------
template<int MODE>
__global__ __launch_bounds__(256) void mfma_gemm_kernel(
    const ushort* __restrict__ A, const ushort* __restrict__ featsp,
    const ushort* __restrict__ Bw, float* __restrict__ Cf,
    ushort* __restrict__ Cb, const float* __restrict__ bias,
    int M, int N, int K) {
  __shared__ ushort As[2][128][32];
  __shared__ ushort Bs[2][128][32];
  const int tid = threadIdx.x;
  const int lane = tid & 63, wid = tid >> 6;
  const int wr = wid >> 1, wc = wid & 1;

  // XCD-chunked swizzle (nwg % 8 == 0 for all our grids -> bijective)
  const int nbn = gridDim.x;
  const int l = blockIdx.y * gridDim.x + blockIdx.x;
  const int nwg = gridDim.x * gridDim.y;
  const int v = (l & 7) * (nwg >> 3) + (l >> 3);
  const int bm = (v / nbn) * 128, bn = (v % nbn) * 128;

  const int lrow = lane & 15, lk = lane >> 4;
  const int swz = (lrow >> 1) & 3;         // read-side chunk permutation

  f32x4_t acc[4][4] = {};

  auto stage = [&](int buf, int kt) {
    int k0 = kt << 5;
#pragma unroll
    for (int it = 0; it < 2; ++it) {
      int idx = it * 256 + tid;
      int row = idx >> 2;
      int c = (((idx & 3) ^ ((idx >> 3) & 3))) * 8;  // logical bf16 offset
      const ushort* ga;
      if (MODE == 0) {
        ga = &A[(size_t)(bm + row) * K + k0 + c];
      } else if (MODE == 1) {
        int p = bm + row;
        int b = p >> 10, n = p & 1023;
        int iw = n >> 5, ih = n & 31;
        ga = &featsp[(((size_t)b * PW + iw + 1) * PW + ih + 1) * 512 + k0 + c];
      } else {
        int p = bm + row;
        int b = p >> 8, sp = p & 255;
        int w2 = sp >> 4, h2 = sp & 15;
        int kk = k0 + c;
        int tap = kk >> 9, ic = kk & 511;
        int kh = tap / 3, kw = tap - 3 * kh;
        ga = &featsp[(((size_t)b * PW + 2 * w2 + kh) * PW + 2 * h2 + kw) * 512 + ic];
      }
      __builtin_amdgcn_global_load_lds((gas_t*)ga,
          (las_t*)(&As[buf][0][0] + (size_t)idx * 8), 16, 0, 0);
      const ushort* gb = &Bw[(size_t)(bn + row) * K + k0 + c];
      __builtin_amdgcn_global_load_lds((gas_t*)gb,
          (las_t*)(&Bs[buf][0][0] + (size_t)idx * 8), 16, 0, 0);
    }
  };

  stage(0, 0);
  const int NT = K >> 5;
  for (int kt = 0; kt < NT; ++kt) {
    int cur = kt & 1;
    __syncthreads();                 // drains vmcnt(0): buf[cur] ready
    if (kt + 1 < NT) stage(cur ^ 1, kt + 1);
    bf16x8 aF[4], bF[4];
#pragma unroll
    for (int m = 0; m < 4; ++m)
      aF[m] = *reinterpret_cast<const bf16x8*>(
          &As[cur][wr * 64 + m * 16 + lrow][(lk ^ swz) * 8]);
#pragma unroll
    for (int n = 0; n < 4; ++n)
      bF[n] = *reinterpret_cast<const bf16x8*>(
          &Bs[cur][wc * 64 + n * 16 + lrow][(lk ^ swz) * 8]);
#pragma unroll
    for (int m = 0; m < 4; ++m)
#pragma unroll
      for (int n = 0; n < 4; ++n)
        acc[m][n] = __builtin_amdgcn_mfma_f32_16x16x32_bf16(
            aF[m], bF[n], acc[m][n], 0, 0, 0);
  }

#pragma unroll
  for (int m = 0; m < 4; ++m) {
#pragma unroll
    for (int n = 0; n < 4; ++n) {
      int col = bn + wc * 64 + n * 16 + lrow;
#pragma unroll
      for (int r = 0; r < 4; ++r) {
        int row = bm + wr * 64 + m * 16 + lk * 4 + r;
        float v2 = acc[m][n][r];
        if (MODE == 2) v2 += bias[col];
        if (MODE == 1) Cb[(size_t)row * N + col] = f2b(v2);
        else Cf[(size_t)row * N + col] = v2;
      }
    }
  }
}

// ---------------------------------------------------------------------------
// LayerNorm over last dim (1024) of conv output kv[8192][1024] (f32).
// K half -> Kb[bh][256][64] row-major (coalesced).
// V half -> Vt[bh][64][256] TRANSPOSED (scatter 2B stores; moves the
// transpose off attention's critical path; L2 absorbs the scatter).
// ---------------------------------------------------------------------------
__global__ __launch_bounds__(256) void ln_kernel(
    const float* __restrict__ kvin, const float* __restrict__ gamma,
    const float* __restrict__ beta, ushort* __restrict__ Kb,
    ushort* __restrict__ Vt) {
  const int p = blockIdx.x, tid = threadIdx.x;
  float4 x = reinterpret_cast<const float4*>(kvin + (size_t)p * CDIM)[tid];
  float s = x.x + x.y + x.z + x.w;
  float ss = x.x * x.x + x.y * x.y + x.z * x.z + x.w * x.w;
#pragma unroll
  for (int off = 32; off > 0; off >>= 1) {
    s += __shfl_down(s, off);
    ss += __shfl_down(ss, off);
  }
  __shared__ float sb[4], ssb[4];
  if ((tid & 63) == 0) { sb[tid >> 6] = s; ssb[tid >> 6] = ss; }
  __syncthreads();
  float tot = sb[0] + sb[1] + sb[2] + sb[3];
  float tot2 = ssb[0] + ssb[1] + ssb[2] + ssb[3];
  float mu = tot * (1.f / CDIM);
  float var = tot2 * (1.f / CDIM) - mu * mu;
  float rstd = rsqrtf(var + EPS_);
  float4 g = reinterpret_cast<const float4*>(gamma)[tid];
  float4 bb = reinterpret_cast<const float4*>(beta)[tid];
  ushort o0 = f2b((x.x - mu) * rstd * g.x + bb.x);
  ushort o1 = f2b((x.y - mu) * rstd * g.y + bb.y);
  ushort o2 = f2b((x.z - mu) * rstd * g.z + bb.z);
  ushort o3 = f2b((x.w - mu) * rstd * g.w + bb.w);
  int b = p >> 8, j = p & 255;
  int c = tid * 4;
  if (c < DIM_) {
    int h = c >> 6, d = c & 63;
    ushort4 o = make_ushort4(o0, o1, o2, o3);
    *reinterpret_cast<ushort4*>(&Kb[(((size_t)(b * 8 + h)) * M2 + j) * HD_ + d]) = o;
  } else {
    int c2 = c - DIM_;
    int h = c2 >> 6, d = c2 & 63;
    size_t base = ((size_t)(b * 8 + h) * HD_ + d) * M2 + j;
    Vt[base]           = o0;
    Vt[base + M2]      = o1;
    Vt[base + 2 * M2]  = o2;
    Vt[base + 3 * M2]  = o3;
  }
}

// ---------------------------------------------------------------------------
// MFMA attention, NO K/V staging (K/V are L2-resident: 64 KB per (b,h),
// shared by 8 q-tile blocks pinned to one XCD via bh-chunked swizzle).
// One block per (qt, bh): 4 waves, each 32 q-rows. Barrier-free.
// LDS = 32 KiB: per-wave 8 KiB P buffer (16 q x 256 kv, XOR-swizzled),
// PV runs in two 16-q halves.
// ---------------------------------------------------------------------------
__global__ __launch_bounds__(256) void attn_mfma_kernel(
    const ushort* __restrict__ qb, const ushort* __restrict__ Kb,
    const ushort* __restrict__ Vt, ushort* __restrict__ attob) {
  __shared__ __align__(16) char lds[32768];
  char* lp = lds;
  const int tid = threadIdx.x;
  const int lane = tid & 63, wid = tid >> 6;
  const int lr = lane & 15, lk = lane >> 4;

  // bh-chunked XCD swizzle: each XCD gets 32 consecutive bh with all 8 qt,
  // so one XCD fetches each (b,h)'s K/V exactly once (L2-resident after).
  const int l = blockIdx.y * 8 + blockIdx.x;       // 2048 blocks
  const int v = (l & 7) * 256 + (l >> 3);
  const int bh = v >> 3, qt = v & 7;
  const int b = bh >> 3, h = bh & 7;

  // P (per-wave 8 KiB): 16 q-rows x 256 kv, bf16, XOR-swizzled
  auto p_byte = [](int w, int q4, int kv) -> int {
    return (w << 13) + (q4 << 9) + (((kv << 1)) ^ ((q4 & 7) << 4));
  };

  const ushort* Khead = Kb + (size_t)bh * M2 * HD_;   // [256][64]
  const ushort* Vthead = Vt + (size_t)bh * HD_ * M2;  // [64][256]

  const int qbase = qt * 128 + wid * 32;
  bf16x8 qf[2][2];
#pragma unroll
  for (int mf = 0; mf < 2; ++mf)
#pragma unroll
    for (int ks = 0; ks < 2; ++ks)
      qf[mf][ks] = *reinterpret_cast<const bf16x8*>(
          qb + ((size_t)(b * N_ + qbase + mf * 16 + lr)) * DIM_ + h * HD_ + ks * 32 + lk * 8);

  // ---- QK^T: S[32 q][256 kv], K fragments straight from L2 ----
  f32x4_t sacc[2][16] = {};
  __builtin_amdgcn_s_setprio(1);
#pragma unroll
  for (int ks = 0; ks < 2; ++ks) {
#pragma unroll
    for (int nj = 0; nj < 16; ++nj) {
      bf16x8 kf = *reinterpret_cast<const bf16x8*>(
          Khead + (size_t)(nj * 16 + lr) * HD_ + ks * 32 + lk * 8);
      sacc[0][nj] = __builtin_amdgcn_mfma_f32_16x16x32_bf16(qf[0][ks], kf, sacc[0][nj], 0, 0, 0);
      sacc[1][nj] = __builtin_amdgcn_mfma_f32_16x16x32_bf16(qf[1][ks], kf, sacc[1][nj], 0, 0, 0);
    }
  }
  __builtin_amdgcn_s_setprio(0);

  float linv[2][4];
  f32x4_t oacc[2][4] = {};
#pragma unroll
  for (int mf = 0; mf < 2; ++mf) {
    // softmax for this 16-q half (no max-subtraction; alpha ~ N(0,0.016))
#pragma unroll
    for (int r = 0; r < 4; ++r) {
      float pv[16];
      float sum = 0.f;
#pragma unroll
      for (int nj = 0; nj < 16; ++nj) {
        pv[nj] = __expf(sacc[mf][nj][r] * SCALE_);
        sum += pv[nj];
      }
      sum += __shfl_xor(sum, 1);
      sum += __shfl_xor(sum, 2);
      sum += __shfl_xor(sum, 4);
      sum += __shfl_xor(sum, 8);
      linv[mf][r] = 1.f / sum;
      int q4 = lk * 4 + r;
#pragma unroll
      for (int nj = 0; nj < 16; ++nj)
        *reinterpret_cast<ushort*>(lp + p_byte(wid, q4, nj * 16 + lr)) = f2b(pv[nj]);
    }
    // PV for this half; V^T fragments straight from L2
    __builtin_amdgcn_s_setprio(1);
#pragma unroll
    for (int ks2 = 0; ks2 < 8; ++ks2) {
      bf16x8 pf = *reinterpret_cast<const bf16x8*>(
          lp + p_byte(wid, lr, ks2 * 32 + lk * 8));
#pragma unroll
      for (int df = 0; df < 4; ++df) {
        bf16x8 vf = *reinterpret_cast<const bf16x8*>(
            Vthead + (size_t)(df * 16 + lr) * M2 + ks2 * 32 + lk * 8);
        oacc[mf][df] = __builtin_amdgcn_mfma_f32_16x16x32_bf16(pf, vf, oacc[mf][df], 0, 0, 0);
      }
    }
    __builtin_amdgcn_s_setprio(0);
  }

#pragma unroll
  for (int mf = 0; mf < 2; ++mf)
#pragma unroll
    for (int df = 0; df < 4; ++df)
#pragma unroll
      for (int r = 0; r < 4; ++r) {
        int qrow = qbase + mf * 16 + lk * 4 + r;
        int dcol = df * 16 + lr;
        float val = oacc[mf][df][r] * linv[mf][r];
        attob[((size_t)(b * N_ + qrow)) * DIM_ + h * HD_ + dcol] = f2b(val);
      }
}

// ---------------------------------------------------------------------------
extern "C" void kernel_launch(void* const* d_in, const int* in_sizes, int n_in,
                              void* d_out, int out_size, void* d_ws, size_t ws_size,
                              hipStream_t stream) {
  const float* feats  = (const float*)d_in[0];
  const float* W_q    = (const float*)d_in[1];
  const float* conv_w = (const float*)d_in[2];
  const float* conv_b = (const float*)d_in[3];
  const float* ln_g   = (const float*)d_in[4];
  const float* ln_b   = (const float*)d_in[5];
  const float* W_out  = (const float*)d_in[6];
  float* out = (float*)d_out;

  const size_t FP_ELEMS = (size_t)B_ * PW * PW * DIM_;   // 18.94M
  char* ws = (char*)d_ws;
  ushort* featsp = (ushort*)ws;  ws += FP_ELEMS * 2;                  // 37.9 MB
  ushort* qb     = (ushort*)ws;  ws += (size_t)B_ * N_ * DIM_ * 2;    // 33.5 MB
  ushort* attob  = (ushort*)ws;  ws += (size_t)B_ * N_ * DIM_ * 2;    // 33.5 MB
  float*  kvf    = (float*)ws;   ws += (size_t)B_ * M2 * CDIM * 4;    // 33.5 MB
  ushort* convwb = (ushort*)ws;  ws += (size_t)CDIM * KCONV * 2;      //  9.4 MB
  ushort* wqb    = (ushort*)ws;  ws += (size_t)DIM_ * DIM_ * 2;       //  0.5 MB
  ushort* woutb  = (ushort*)ws;  ws += (size_t)DIM_ * DIM_ * 2;       //  0.5 MB
  ushort* Kb     = (ushort*)ws;  ws += (size_t)B_ * HEAD_ * M2 * HD_ * 2;  // 8.4 MB
  ushort* Vt     = (ushort*)ws;  ws += (size_t)B_ * HEAD_ * M2 * HD_ * 2;  // 8.4 MB

  // padded bf16 feats: zero only the halo border, then fill interior
  zero_border_kernel<<<1056, 256, 0, stream>>>(featsp);
  cast_featsp_kernel<<<16384, 256, 0, stream>>>(feats, featsp);
  cast_f32_bf16_kernel<<<256, 256, 0, stream>>>(W_q, wqb, (DIM_ * DIM_) / 4);
  cast_f32_bf16_kernel<<<256, 256, 0, stream>>>(W_out, woutb, (DIM_ * DIM_) / 4);
  permute_convw_kernel<<<dim3(18, CDIM), 256, 0, stream>>>(conv_w, convwb);

  // q = feats @ W_q^T  -> bf16  (A gathered from padded feats, center tap)
  mfma_gemm_kernel<1><<<dim3(DIM_ / 128, (B_ * N_) / 128), 256, 0, stream>>>(
      nullptr, featsp, wqb, nullptr, qb, nullptr, B_ * N_, DIM_, DIM_);

  // kv_pre = conv(feats) + bias (implicit im2col from padded feats)
  mfma_gemm_kernel<2><<<dim3(CDIM / 128, (B_ * M2) / 128), 256, 0, stream>>>(
      nullptr, featsp, convwb, kvf, nullptr, conv_b, B_ * M2, CDIM, KCONV);

  // LayerNorm -> Kb (row-major) + Vt (transposed)
  ln_kernel<<<B_ * M2, 256, 0, stream>>>(kvf, ln_g, ln_b, Kb, Vt);

  // MFMA attention (staging-free, L2-fed) -> attob (bf16)
  attn_mfma_kernel<<<dim3(8, B_ * HEAD_), 256, 0, stream>>>(qb, Kb, Vt, attob);

  // out = attout @ W_out^T
  mfma_gemm_kernel<0><<<dim3(DIM_ / 128, (B_ * N_) / 128), 256, 0, stream>>>(
      attob, nullptr, woutb, out, nullptr, nullptr, B_ * N_, DIM_, DIM_);
}

// Round 9
// 328.073 us; speedup vs baseline: 1.0966x; 1.0966x over previous
//
#include <hip/hip_runtime.h>
#include <hip/hip_bf16.h>
#include <math.h>

// Problem constants
#define B_    32
#define N_    1024
#define DIM_  512
#define HEAD_ 8
#define HD_   64        // head dim
#define WSP   32        // sqrt(N)
#define M2    256       // kv spatial positions (16*16)
#define CDIM  1024      // 2*DIM
#define KCONV 4608      // DIM*3*3
#define EPS_  1e-5f
#define SCALE_ 0.044194173824159216f  // DIM^-0.5
#define PW    34        // padded spatial side (32 + 2 halo)

typedef __attribute__((ext_vector_type(8))) short bf16x8;
typedef __attribute__((ext_vector_type(4))) float f32x4_t;
typedef const __attribute__((address_space(1))) void gas_t;   // global addr space
typedef __attribute__((address_space(3))) void las_t;         // LDS addr space

__device__ __forceinline__ ushort f2b(float x) {
  __hip_bfloat16 h = __float2bfloat16(x);
  return *reinterpret_cast<const ushort*>(&h);
}

// ---------------------------------------------------------------------------
// fp32 -> bf16 cast, 4 elems/thread (weights)
// ---------------------------------------------------------------------------
__global__ __launch_bounds__(256) void cast_f32_bf16_kernel(
    const float* __restrict__ in, ushort* __restrict__ out, int n4) {
  int i = blockIdx.x * 256 + threadIdx.x;
  if (i >= n4) return;
  float4 v = reinterpret_cast<const float4*>(in)[i];
  ushort4 o;
  o.x = f2b(v.x); o.y = f2b(v.y); o.z = f2b(v.z); o.w = f2b(v.w);
  reinterpret_cast<ushort4*>(out)[i] = o;
}

// ---------------------------------------------------------------------------
// Zero only the halo border of featsp [b][34][34][512]
// ---------------------------------------------------------------------------
__global__ __launch_bounds__(256) void zero_border_kernel(ushort* __restrict__ featsp) {
  int t = blockIdx.x * 256 + threadIdx.x;
  int b = t / 8448, r = t - b * 8448;          // 8448 = 132*64
  int cell = r >> 6, ic8 = (r & 63) * 8;
  int iw, ih;
  if (cell < 34)      { iw = 0;  ih = cell; }
  else if (cell < 68) { iw = 33; ih = cell - 34; }
  else { int e = cell - 68; iw = 1 + (e >> 1); ih = (e & 1) * 33; }
  bf16x8 z = {};
  *reinterpret_cast<bf16x8*>(&featsp[(((size_t)b * PW + iw) * PW + ih) * 512 + ic8]) = z;
}

// ---------------------------------------------------------------------------
// feats f32 [b][n=iw*32+ih][ic] -> zero-padded bf16 [b][iw+1][ih+1][ic]
// ---------------------------------------------------------------------------
__global__ __launch_bounds__(256) void cast_featsp_kernel(
    const float* __restrict__ feats, ushort* __restrict__ featsp) {
  int i = blockIdx.x * 256 + threadIdx.x;       // ushort4 index
  int e = i * 4;
  int b = e >> 19, r = e & 524287;
  int n = r >> 9, ic = r & 511;
  int iw = n >> 5, ih = n & 31;
  float4 v = reinterpret_cast<const float4*>(feats)[i];
  ushort4 o;
  o.x = f2b(v.x); o.y = f2b(v.y); o.z = f2b(v.z); o.w = f2b(v.w);
  size_t dst = (((size_t)b * PW + iw + 1) * PW + ih + 1) * 512 + ic;
  *reinterpret_cast<ushort4*>(&featsp[dst]) = o;
}

// ---------------------------------------------------------------------------
// conv_w [oc][ic*9 + tap] fp32 -> bf16 [oc][tap*512 + ic]
// ---------------------------------------------------------------------------
__global__ __launch_bounds__(256) void permute_convw_kernel(
    const float* __restrict__ in, ushort* __restrict__ out) {
  int oc = blockIdx.y;
  int idx = blockIdx.x * 256 + threadIdx.x;  // [0, 4608)
  int tap = idx >> 9, ic = idx & 511;
  out[(size_t)oc * KCONV + idx] = f2b(in[(size_t)oc * KCONV + ic * 9 + tap]);
}

// ---------------------------------------------------------------------------
// Shared MFMA GEMM body: C[M x N] = A[M x K] * B[N x K]^T
// 128x128 tile, BK=32, 4 waves, LDS double-buffer, global_load_lds(16B),
// 2-phase loop, XCD-chunked swizzle (l/nbn/nwg passed in), conflict-free
// LDS via source-permuted chunk swizzle.
// MODE 0: A = plain bf16 buffer            -> C f32
// MODE 1: A = padded-feats center-tap rows -> C bf16   (q-proj)
// MODE 2: A = padded-feats im2col 3x3 s2   -> C f32 + bias (conv)
// ---------------------------------------------------------------------------
template<int MODE>
__device__ __forceinline__ void gemm_body(
    ushort (*As)[128][32], ushort (*Bs)[128][32],
    int l, int nbn, int nwg,
    const ushort* __restrict__ A, const ushort* __restrict__ featsp,
    const ushort* __restrict__ Bw, float* __restrict__ Cf,
    ushort* __restrict__ Cb, const float* __restrict__ bias,
    int M, int N, int K) {
  const int tid = threadIdx.x;
  const int lane = tid & 63, wid = tid >> 6;
  const int wr = wid >> 1, wc = wid & 1;
  const int v = (l & 7) * (nwg >> 3) + (l >> 3);
  const int bm = (v / nbn) * 128, bn = (v % nbn) * 128;
  const int lrow = lane & 15, lk = lane >> 4;
  const int swz = (lrow >> 1) & 3;         // read-side chunk permutation

  f32x4_t acc[4][4] = {};

  auto stage = [&](int buf, int kt) {
    int k0 = kt << 5;
#pragma unroll
    for (int it = 0; it < 2; ++it) {
      int idx = it * 256 + tid;
      int row = idx >> 2;
      int c = (((idx & 3) ^ ((idx >> 3) & 3))) * 8;  // logical bf16 offset
      const ushort* ga;
      if (MODE == 0) {
        ga = &A[(size_t)(bm + row) * K + k0 + c];
      } else if (MODE == 1) {
        int p = bm + row;
        int b = p >> 10, n = p & 1023;
        int iw = n >> 5, ih = n & 31;
        ga = &featsp[(((size_t)b * PW + iw + 1) * PW + ih + 1) * 512 + k0 + c];
      } else {
        int p = bm + row;
        int b = p >> 8, sp = p & 255;
        int w2 = sp >> 4, h2 = sp & 15;
        int kk = k0 + c;
        int tap = kk >> 9, ic = kk & 511;
        int kh = tap / 3, kw = tap - 3 * kh;
        ga = &featsp[(((size_t)b * PW + 2 * w2 + kh) * PW + 2 * h2 + kw) * 512 + ic];
      }
      __builtin_amdgcn_global_load_lds((gas_t*)ga,
          (las_t*)(&As[buf][0][0] + (size_t)idx * 8), 16, 0, 0);
      const ushort* gb = &Bw[(size_t)(bn + row) * K + k0 + c];
      __builtin_amdgcn_global_load_lds((gas_t*)gb,
          (las_t*)(&Bs[buf][0][0] + (size_t)idx * 8), 16, 0, 0);
    }
  };

  stage(0, 0);
  const int NT = K >> 5;
  for (int kt = 0; kt < NT; ++kt) {
    int cur = kt & 1;
    __syncthreads();                 // drains vmcnt(0): buf[cur] ready
    if (kt + 1 < NT) stage(cur ^ 1, kt + 1);
    bf16x8 aF[4], bF[4];
#pragma unroll
    for (int m = 0; m < 4; ++m)
      aF[m] = *reinterpret_cast<const bf16x8*>(
          &As[cur][wr * 64 + m * 16 + lrow][(lk ^ swz) * 8]);
#pragma unroll
    for (int n = 0; n < 4; ++n)
      bF[n] = *reinterpret_cast<const bf16x8*>(
          &Bs[cur][wc * 64 + n * 16 + lrow][(lk ^ swz) * 8]);
#pragma unroll
    for (int m = 0; m < 4; ++m)
#pragma unroll
      for (int n = 0; n < 4; ++n)
        acc[m][n] = __builtin_amdgcn_mfma_f32_16x16x32_bf16(
            aF[m], bF[n], acc[m][n], 0, 0, 0);
  }

#pragma unroll
  for (int m = 0; m < 4; ++m) {
#pragma unroll
    for (int n = 0; n < 4; ++n) {
      int col = bn + wc * 64 + n * 16 + lrow;
#pragma unroll
      for (int r = 0; r < 4; ++r) {
        int row = bm + wr * 64 + m * 16 + lk * 4 + r;
        float v2 = acc[m][n][r];
        if (MODE == 2) v2 += bias[col];
        if (MODE == 1) Cb[(size_t)row * N + col] = f2b(v2);
        else Cf[(size_t)row * N + col] = v2;
      }
    }
  }
}

// Fused conv (blocks 0..511) + q-proj (blocks 512..1535): both read featsp,
// are independent, and individually grid-limited (conv alone = 2 blocks/CU).
// Co-dispatch fills the machine (~5 blocks/CU) during the conv phase.
__global__ __launch_bounds__(256) void fused_convq_kernel(
    const ushort* __restrict__ featsp, const ushort* __restrict__ convwb,
    const ushort* __restrict__ wqb, const float* __restrict__ conv_b,
    float* __restrict__ kvf, ushort* __restrict__ qb) {
  __shared__ ushort As[2][128][32];
  __shared__ ushort Bs[2][128][32];
  if (blockIdx.x < 512)
    gemm_body<2>(As, Bs, blockIdx.x, 8, 512,
                 nullptr, featsp, convwb, kvf, nullptr, conv_b,
                 B_ * M2, CDIM, KCONV);
  else
    gemm_body<1>(As, Bs, blockIdx.x - 512, 4, 1024,
                 nullptr, featsp, wqb, nullptr, qb, nullptr,
                 B_ * N_, DIM_, DIM_);
}

// out-proj (MODE 0), standalone
__global__ __launch_bounds__(256) void gemm0_kernel(
    const ushort* __restrict__ A, const ushort* __restrict__ Bw,
    float* __restrict__ Cf, int M, int N, int K) {
  __shared__ ushort As[2][128][32];
  __shared__ ushort Bs[2][128][32];
  int l = blockIdx.y * gridDim.x + blockIdx.x;
  gemm_body<0>(As, Bs, l, gridDim.x, gridDim.x * gridDim.y,
               A, nullptr, Bw, Cf, nullptr, nullptr, M, N, K);
}

// ---------------------------------------------------------------------------
// LayerNorm over last dim (1024) of conv output kv[8192][1024] (f32).
// K half -> Kb[bh][256][64] row-major; V half -> Vt[bh][64][256] transposed
// (scatter 2B stores; moves the transpose off attention's critical path).
// ---------------------------------------------------------------------------
__global__ __launch_bounds__(256) void ln_kernel(
    const float* __restrict__ kvin, const float* __restrict__ gamma,
    const float* __restrict__ beta, ushort* __restrict__ Kb,
    ushort* __restrict__ Vt) {
  const int p = blockIdx.x, tid = threadIdx.x;
  float4 x = reinterpret_cast<const float4*>(kvin + (size_t)p * CDIM)[tid];
  float s = x.x + x.y + x.z + x.w;
  float ss = x.x * x.x + x.y * x.y + x.z * x.z + x.w * x.w;
#pragma unroll
  for (int off = 32; off > 0; off >>= 1) {
    s += __shfl_down(s, off);
    ss += __shfl_down(ss, off);
  }
  __shared__ float sb[4], ssb[4];
  if ((tid & 63) == 0) { sb[tid >> 6] = s; ssb[tid >> 6] = ss; }
  __syncthreads();
  float tot = sb[0] + sb[1] + sb[2] + sb[3];
  float tot2 = ssb[0] + ssb[1] + ssb[2] + ssb[3];
  float mu = tot * (1.f / CDIM);
  float var = tot2 * (1.f / CDIM) - mu * mu;
  float rstd = rsqrtf(var + EPS_);
  float4 g = reinterpret_cast<const float4*>(gamma)[tid];
  float4 bb = reinterpret_cast<const float4*>(beta)[tid];
  ushort o0 = f2b((x.x - mu) * rstd * g.x + bb.x);
  ushort o1 = f2b((x.y - mu) * rstd * g.y + bb.y);
  ushort o2 = f2b((x.z - mu) * rstd * g.z + bb.z);
  ushort o3 = f2b((x.w - mu) * rstd * g.w + bb.w);
  int b = p >> 8, j = p & 255;
  int c = tid * 4;
  if (c < DIM_) {
    int h = c >> 6, d = c & 63;
    ushort4 o = make_ushort4(o0, o1, o2, o3);
    *reinterpret_cast<ushort4*>(&Kb[(((size_t)(b * 8 + h)) * M2 + j) * HD_ + d]) = o;
  } else {
    int c2 = c - DIM_;
    int h = c2 >> 6, d = c2 & 63;
    size_t base = ((size_t)(b * 8 + h) * HD_ + d) * M2 + j;
    Vt[base]           = o0;
    Vt[base + M2]      = o1;
    Vt[base + 2 * M2]  = o2;
    Vt[base + 3 * M2]  = o3;
  }
}

// ---------------------------------------------------------------------------
// MFMA attention. One block per (qt, bh): 4 waves, each 32 q-rows.
// LDS = 64 KiB: K swizzled [256][64] in [0,32K) and V^T swizzled [64][256]
// in [32K,64K), BOTH staged via global_load_lds(16B) with source
// pre-swizzle (Vt is already transposed in global by LN). After QK^T the
// K region is dead and is reused for the per-wave P buffer (8 KiB each),
// PV split in two 16-q halves. 2 blocks/CU.
// ---------------------------------------------------------------------------
__global__ __launch_bounds__(256) void attn_mfma_kernel(
    const ushort* __restrict__ qb, const ushort* __restrict__ Kb,
    const ushort* __restrict__ Vt, ushort* __restrict__ attob) {
  __shared__ __align__(16) char lds[65536];
  char* lp = lds;
  const int tid = threadIdx.x;
  const int lane = tid & 63, wid = tid >> 6;
  const int lr = lane & 15, lk = lane >> 4;

  // bh-chunked XCD swizzle: each XCD owns 32 consecutive bh with all 8 qt
  const int l = blockIdx.y * 8 + blockIdx.x;       // 2048 blocks
  const int v = (l & 7) * 256 + (l >> 3);
  const int bh = v >> 3, qt = v & 7;
  const int b = bh >> 3, h = bh & 7;

  auto ks_byte = [](int j, int d) -> int {            // K[256][64]
    return (j << 7) + (((d << 1)) ^ ((j & 7) << 4));
  };
  auto vt_byte = [](int d, int j) -> int {            // V^T[64][256]
    return 32768 + (d << 9) + (((j << 1)) ^ ((d & 7) << 4));
  };
  // P (in dead K region): per-wave 8 KiB, 16 q-rows x 256 kv, bf16
  auto p_byte = [](int w, int q4, int kv) -> int {
    return (w << 13) + (q4 << 9) + (((kv << 1)) ^ ((q4 & 7) << 4));
  };

  const ushort* Khead  = Kb + (size_t)bh * M2 * HD_;   // [256][64]
  const ushort* Vthead = Vt + (size_t)bh * HD_ * M2;   // [64][256]

  // ---- stage K and V^T via global_load_lds, source pre-swizzled ----
#pragma unroll
  for (int it = 0; it < 8; ++it) {
    int o = (it * 256 + tid) * 16;                 // K region byte offset
    int j = o >> 7, c = (o >> 4) & 7;
    int cl = c ^ (j & 7);                          // logical chunk
    __builtin_amdgcn_global_load_lds((gas_t*)(Khead + j * HD_ + cl * 8),
        (las_t*)(lp + o), 16, 0, 0);
  }
#pragma unroll
  for (int it = 0; it < 8; ++it) {
    int o = (it * 256 + tid) * 16;                 // V^T region byte offset
    int d = o >> 9, c = (o >> 4) & 31;
    int cl = c ^ (d & 7);
    __builtin_amdgcn_global_load_lds((gas_t*)(Vthead + d * M2 + cl * 8),
        (las_t*)(lp + 32768 + o), 16, 0, 0);
  }

  const int qbase = qt * 128 + wid * 32;
  bf16x8 qf[2][2];
#pragma unroll
  for (int mf = 0; mf < 2; ++mf)
#pragma unroll
    for (int ks = 0; ks < 2; ++ks)
      qf[mf][ks] = *reinterpret_cast<const bf16x8*>(
          qb + ((size_t)(b * N_ + qbase + mf * 16 + lr)) * DIM_ + h * HD_ + ks * 32 + lk * 8);

  __syncthreads();   // staging complete (drains vmcnt)

  // ---- QK^T: S[32 q][256 kv] ----
  f32x4_t sacc[2][16] = {};
  __builtin_amdgcn_s_setprio(1);
#pragma unroll
  for (int ks = 0; ks < 2; ++ks) {
#pragma unroll
    for (int nj = 0; nj < 16; ++nj) {
      bf16x8 kf = *reinterpret_cast<const bf16x8*>(
          lp + ks_byte(nj * 16 + lr, ks * 32 + lk * 8));
      sacc[0][nj] = __builtin_amdgcn_mfma_f32_16x16x32_bf16(qf[0][ks], kf, sacc[0][nj], 0, 0, 0);
      sacc[1][nj] = __builtin_amdgcn_mfma_f32_16x16x32_bf16(qf[1][ks], kf, sacc[1][nj], 0, 0, 0);
    }
  }
  __builtin_amdgcn_s_setprio(0);

  __syncthreads();   // ALL waves done reading K -> K region reusable for P

  float linv[2][4];
  f32x4_t oacc[2][4] = {};
#pragma unroll
  for (int mf = 0; mf < 2; ++mf) {
    // softmax for this 16-q half (no max-subtraction; alpha ~ N(0,0.016))
#pragma unroll
    for (int r = 0; r < 4; ++r) {
      float pv[16];
      float sum = 0.f;
#pragma unroll
      for (int nj = 0; nj < 16; ++nj) {
        pv[nj] = __expf(sacc[mf][nj][r] * SCALE_);
        sum += pv[nj];
      }
      sum += __shfl_xor(sum, 1);
      sum += __shfl_xor(sum, 2);
      sum += __shfl_xor(sum, 4);
      sum += __shfl_xor(sum, 8);
      linv[mf][r] = 1.f / sum;
      int q4 = lk * 4 + r;
#pragma unroll
      for (int nj = 0; nj < 16; ++nj)
        *reinterpret_cast<ushort*>(lp + p_byte(wid, q4, nj * 16 + lr)) = f2b(pv[nj]);
    }
    // PV for this half (per-wave private P region; in-wave LDS ordering)
    __builtin_amdgcn_s_setprio(1);
#pragma unroll
    for (int ks2 = 0; ks2 < 8; ++ks2) {
      bf16x8 pf = *reinterpret_cast<const bf16x8*>(
          lp + p_byte(wid, lr, ks2 * 32 + lk * 8));
#pragma unroll
      for (int df = 0; df < 4; ++df) {
        bf16x8 vf = *reinterpret_cast<const bf16x8*>(
            lp + vt_byte(df * 16 + lr, ks2 * 32 + lk * 8));
        oacc[mf][df] = __builtin_amdgcn_mfma_f32_16x16x32_bf16(pf, vf, oacc[mf][df], 0, 0, 0);
      }
    }
    __builtin_amdgcn_s_setprio(0);
  }

#pragma unroll
  for (int mf = 0; mf < 2; ++mf)
#pragma unroll
    for (int df = 0; df < 4; ++df)
#pragma unroll
      for (int r = 0; r < 4; ++r) {
        int qrow = qbase + mf * 16 + lk * 4 + r;
        int dcol = df * 16 + lr;
        float val = oacc[mf][df][r] * linv[mf][r];
        attob[((size_t)(b * N_ + qrow)) * DIM_ + h * HD_ + dcol] = f2b(val);
      }
}

// ---------------------------------------------------------------------------
extern "C" void kernel_launch(void* const* d_in, const int* in_sizes, int n_in,
                              void* d_out, int out_size, void* d_ws, size_t ws_size,
                              hipStream_t stream) {
  const float* feats  = (const float*)d_in[0];
  const float* W_q    = (const float*)d_in[1];
  const float* conv_w = (const float*)d_in[2];
  const float* conv_b = (const float*)d_in[3];
  const float* ln_g   = (const float*)d_in[4];
  const float* ln_b   = (const float*)d_in[5];
  const float* W_out  = (const float*)d_in[6];
  float* out = (float*)d_out;

  const size_t FP_ELEMS = (size_t)B_ * PW * PW * DIM_;   // 18.94M
  char* ws = (char*)d_ws;
  ushort* featsp = (ushort*)ws;  ws += FP_ELEMS * 2;                  // 37.9 MB
  ushort* qb     = (ushort*)ws;  ws += (size_t)B_ * N_ * DIM_ * 2;    // 33.5 MB
  ushort* attob  = (ushort*)ws;  ws += (size_t)B_ * N_ * DIM_ * 2;    // 33.5 MB
  float*  kvf    = (float*)ws;   ws += (size_t)B_ * M2 * CDIM * 4;    // 33.5 MB
  ushort* convwb = (ushort*)ws;  ws += (size_t)CDIM * KCONV * 2;      //  9.4 MB
  ushort* wqb    = (ushort*)ws;  ws += (size_t)DIM_ * DIM_ * 2;       //  0.5 MB
  ushort* woutb  = (ushort*)ws;  ws += (size_t)DIM_ * DIM_ * 2;       //  0.5 MB
  ushort* Kb     = (ushort*)ws;  ws += (size_t)B_ * HEAD_ * M2 * HD_ * 2;  // 8.4 MB
  ushort* Vt     = (ushort*)ws;  ws += (size_t)B_ * HEAD_ * M2 * HD_ * 2;  // 8.4 MB

  // padded bf16 feats: zero only the halo border, then fill interior
  zero_border_kernel<<<1056, 256, 0, stream>>>(featsp);
  cast_featsp_kernel<<<16384, 256, 0, stream>>>(feats, featsp);
  cast_f32_bf16_kernel<<<256, 256, 0, stream>>>(W_q, wqb, (DIM_ * DIM_) / 4);
  cast_f32_bf16_kernel<<<256, 256, 0, stream>>>(W_out, woutb, (DIM_ * DIM_) / 4);
  permute_convw_kernel<<<dim3(18, CDIM), 256, 0, stream>>>(conv_w, convwb);

  // fused: conv (512 blocks) + q-proj (1024 blocks)
  fused_convq_kernel<<<1536, 256, 0, stream>>>(
      featsp, convwb, wqb, conv_b, kvf, qb);

  // LayerNorm -> Kb (row-major) + Vt (transposed)
  ln_kernel<<<B_ * M2, 256, 0, stream>>>(kvf, ln_g, ln_b, Kb, Vt);

  // MFMA attention (K + V^T LDS-staged via global_load_lds) -> attob
  attn_mfma_kernel<<<dim3(8, B_ * HEAD_), 256, 0, stream>>>(qb, Kb, Vt, attob);

  // out = attout @ W_out^T
  gemm0_kernel<<<dim3(DIM_ / 128, (B_ * N_) / 128), 256, 0, stream>>>(
      attob, woutb, out, B_ * N_, DIM_, DIM_);
}

// Round 10
// 293.962 us; speedup vs baseline: 1.2239x; 1.1160x over previous
//
#include <hip/hip_runtime.h>
#include <hip/hip_bf16.h>
#include <math.h>

// Problem constants
#define B_    32
#define N_    1024
#define DIM_  512
#define HEAD_ 8
#define HD_   64        // head dim
#define WSP   32        // sqrt(N)
#define M2    256       // kv spatial positions (16*16)
#define CDIM  1024      // 2*DIM
#define KCONV 4608      // DIM*3*3
#define EPS_  1e-5f
#define SCALE_ 0.044194173824159216f  // DIM^-0.5
#define PW    34        // padded spatial side (32 + 2 halo)

typedef __attribute__((ext_vector_type(8))) short bf16x8;
typedef __attribute__((ext_vector_type(4))) float f32x4_t;
typedef const __attribute__((address_space(1))) void gas_t;   // global addr space
typedef __attribute__((address_space(3))) void las_t;         // LDS addr space

__device__ __forceinline__ ushort f2b(float x) {
  __hip_bfloat16 h = __float2bfloat16(x);
  return *reinterpret_cast<const ushort*>(&h);
}

// ---------------------------------------------------------------------------
// fp32 -> bf16 cast, 4 elems/thread (weights)
// ---------------------------------------------------------------------------
__global__ __launch_bounds__(256) void cast_f32_bf16_kernel(
    const float* __restrict__ in, ushort* __restrict__ out, int n4) {
  int i = blockIdx.x * 256 + threadIdx.x;
  if (i >= n4) return;
  float4 v = reinterpret_cast<const float4*>(in)[i];
  ushort4 o;
  o.x = f2b(v.x); o.y = f2b(v.y); o.z = f2b(v.z); o.w = f2b(v.w);
  reinterpret_cast<ushort4*>(out)[i] = o;
}

// ---------------------------------------------------------------------------
// Zero only the halo border of featsp [b][34][34][512]
// ---------------------------------------------------------------------------
__global__ __launch_bounds__(256) void zero_border_kernel(ushort* __restrict__ featsp) {
  int t = blockIdx.x * 256 + threadIdx.x;
  int b = t / 8448, r = t - b * 8448;          // 8448 = 132*64
  int cell = r >> 6, ic8 = (r & 63) * 8;
  int iw, ih;
  if (cell < 34)      { iw = 0;  ih = cell; }
  else if (cell < 68) { iw = 33; ih = cell - 34; }
  else { int e = cell - 68; iw = 1 + (e >> 1); ih = (e & 1) * 33; }
  bf16x8 z = {};
  *reinterpret_cast<bf16x8*>(&featsp[(((size_t)b * PW + iw) * PW + ih) * 512 + ic8]) = z;
}

// ---------------------------------------------------------------------------
// feats f32 [b][n=iw*32+ih][ic] -> zero-padded bf16 [b][iw+1][ih+1][ic]
// ---------------------------------------------------------------------------
__global__ __launch_bounds__(256) void cast_featsp_kernel(
    const float* __restrict__ feats, ushort* __restrict__ featsp) {
  int i = blockIdx.x * 256 + threadIdx.x;       // ushort4 index
  int e = i * 4;
  int b = e >> 19, r = e & 524287;
  int n = r >> 9, ic = r & 511;
  int iw = n >> 5, ih = n & 31;
  float4 v = reinterpret_cast<const float4*>(feats)[i];
  ushort4 o;
  o.x = f2b(v.x); o.y = f2b(v.y); o.z = f2b(v.z); o.w = f2b(v.w);
  size_t dst = (((size_t)b * PW + iw + 1) * PW + ih + 1) * 512 + ic;
  *reinterpret_cast<ushort4*>(&featsp[dst]) = o;
}

// ---------------------------------------------------------------------------
// conv_w [oc][ic*9 + tap] fp32 -> bf16 [oc][tap*512 + ic]
// ---------------------------------------------------------------------------
__global__ __launch_bounds__(256) void permute_convw_kernel(
    const float* __restrict__ in, ushort* __restrict__ out) {
  int oc = blockIdx.y;
  int idx = blockIdx.x * 256 + threadIdx.x;  // [0, 4608)
  int tap = idx >> 9, ic = idx & 511;
  out[(size_t)oc * KCONV + idx] = f2b(in[(size_t)oc * KCONV + ic * 9 + tap]);
}

// ---------------------------------------------------------------------------
// Shared MFMA GEMM body: C[M x N] = A[M x K] * B[N x K]^T
// 128x128 tile, BK=32, 4 waves, LDS double-buffer, global_load_lds(16B),
// T4 counted-vmcnt pipeline:
//   stage(next) ; s_waitcnt vmcnt(4) ; s_barrier   <- cur ready, next in flight
//   MFMA(cur)   ; s_barrier                        <- cur reads done, reusable
// XCD-chunked swizzle, conflict-free LDS via source-permuted chunk swizzle.
// MODE 0: A = plain bf16 buffer            -> C f32
// MODE 1: A = padded-feats center-tap rows -> C bf16   (q-proj)
// MODE 2: A = padded-feats im2col 3x3 s2   -> C f32 + bias (conv)
// ---------------------------------------------------------------------------
template<int MODE>
__device__ __forceinline__ void gemm_body(
    ushort (*As)[128][32], ushort (*Bs)[128][32],
    int l, int nbn, int nwg,
    const ushort* __restrict__ A, const ushort* __restrict__ featsp,
    const ushort* __restrict__ Bw, float* __restrict__ Cf,
    ushort* __restrict__ Cb, const float* __restrict__ bias,
    int M, int N, int K) {
  const int tid = threadIdx.x;
  const int lane = tid & 63, wid = tid >> 6;
  const int wr = wid >> 1, wc = wid & 1;
  const int v = (l & 7) * (nwg >> 3) + (l >> 3);
  const int bm = (v / nbn) * 128, bn = (v % nbn) * 128;
  const int lrow = lane & 15, lk = lane >> 4;
  const int swz = (lrow >> 1) & 3;         // read-side chunk permutation

  f32x4_t acc[4][4] = {};

  auto stage = [&](int buf, int kt) {
    int k0 = kt << 5;
#pragma unroll
    for (int it = 0; it < 2; ++it) {
      int idx = it * 256 + tid;
      int row = idx >> 2;
      int c = (((idx & 3) ^ ((idx >> 3) & 3))) * 8;  // logical bf16 offset
      const ushort* ga;
      if (MODE == 0) {
        ga = &A[(size_t)(bm + row) * K + k0 + c];
      } else if (MODE == 1) {
        int p = bm + row;
        int b = p >> 10, n = p & 1023;
        int iw = n >> 5, ih = n & 31;
        ga = &featsp[(((size_t)b * PW + iw + 1) * PW + ih + 1) * 512 + k0 + c];
      } else {
        int p = bm + row;
        int b = p >> 8, sp = p & 255;
        int w2 = sp >> 4, h2 = sp & 15;
        int kk = k0 + c;
        int tap = kk >> 9, ic = kk & 511;
        int kh = tap / 3, kw = tap - 3 * kh;
        ga = &featsp[(((size_t)b * PW + 2 * w2 + kh) * PW + 2 * h2 + kw) * 512 + ic];
      }
      __builtin_amdgcn_global_load_lds((gas_t*)ga,
          (las_t*)(&As[buf][0][0] + (size_t)idx * 8), 16, 0, 0);
      const ushort* gb = &Bw[(size_t)(bn + row) * K + k0 + c];
      __builtin_amdgcn_global_load_lds((gas_t*)gb,
          (las_t*)(&Bs[buf][0][0] + (size_t)idx * 8), 16, 0, 0);
    }
  };

  stage(0, 0);                             // 4 loads in flight
  const int NT = K >> 5;
  for (int kt = 0; kt < NT; ++kt) {
    int cur = kt & 1;
    if (kt + 1 < NT) {
      stage(cur ^ 1, kt + 1);              // 8 in flight
      asm volatile("s_waitcnt vmcnt(4)" ::: "memory");   // cur's 4 retired
    } else {
      asm volatile("s_waitcnt vmcnt(0)" ::: "memory");
    }
    __builtin_amdgcn_s_barrier();          // all waves: cur globally ready
    __builtin_amdgcn_sched_barrier(0);
    bf16x8 aF[4], bF[4];
#pragma unroll
    for (int m = 0; m < 4; ++m)
      aF[m] = *reinterpret_cast<const bf16x8*>(
          &As[cur][wr * 64 + m * 16 + lrow][(lk ^ swz) * 8]);
#pragma unroll
    for (int n = 0; n < 4; ++n)
      bF[n] = *reinterpret_cast<const bf16x8*>(
          &Bs[cur][wc * 64 + n * 16 + lrow][(lk ^ swz) * 8]);
#pragma unroll
    for (int m = 0; m < 4; ++m)
#pragma unroll
      for (int n = 0; n < 4; ++n)
        acc[m][n] = __builtin_amdgcn_mfma_f32_16x16x32_bf16(
            aF[m], bF[n], acc[m][n], 0, 0, 0);
    __builtin_amdgcn_sched_barrier(0);
    __builtin_amdgcn_s_barrier();          // cur reads done -> reusable
  }

#pragma unroll
  for (int m = 0; m < 4; ++m) {
#pragma unroll
    for (int n = 0; n < 4; ++n) {
      int col = bn + wc * 64 + n * 16 + lrow;
#pragma unroll
      for (int r = 0; r < 4; ++r) {
        int row = bm + wr * 64 + m * 16 + lk * 4 + r;
        float v2 = acc[m][n][r];
        if (MODE == 2) v2 += bias[col];
        if (MODE == 1) Cb[(size_t)row * N + col] = f2b(v2);
        else Cf[(size_t)row * N + col] = v2;
      }
    }
  }
}

// conv (MODE 2)
__global__ __launch_bounds__(256) void conv_kernel(
    const ushort* __restrict__ featsp, const ushort* __restrict__ convwb,
    const float* __restrict__ conv_b, float* __restrict__ kvf) {
  __shared__ ushort As[2][128][32];
  __shared__ ushort Bs[2][128][32];
  int l = blockIdx.y * gridDim.x + blockIdx.x;
  gemm_body<2>(As, Bs, l, gridDim.x, gridDim.x * gridDim.y,
               nullptr, featsp, convwb, kvf, nullptr, conv_b,
               B_ * M2, CDIM, KCONV);
}

// q-proj (MODE 1)
__global__ __launch_bounds__(256) void qproj_kernel(
    const ushort* __restrict__ featsp, const ushort* __restrict__ wqb,
    ushort* __restrict__ qb) {
  __shared__ ushort As[2][128][32];
  __shared__ ushort Bs[2][128][32];
  int l = blockIdx.y * gridDim.x + blockIdx.x;
  gemm_body<1>(As, Bs, l, gridDim.x, gridDim.x * gridDim.y,
               nullptr, featsp, wqb, nullptr, qb, nullptr,
               B_ * N_, DIM_, DIM_);
}

// out-proj (MODE 0)
__global__ __launch_bounds__(256) void gemm0_kernel(
    const ushort* __restrict__ A, const ushort* __restrict__ Bw,
    float* __restrict__ Cf, int M, int N, int K) {
  __shared__ ushort As[2][128][32];
  __shared__ ushort Bs[2][128][32];
  int l = blockIdx.y * gridDim.x + blockIdx.x;
  gemm_body<0>(As, Bs, l, gridDim.x, gridDim.x * gridDim.y,
               A, nullptr, Bw, Cf, nullptr, nullptr, M, N, K);
}

// ---------------------------------------------------------------------------
// LayerNorm over last dim (1024) of conv output kv[8192][1024] (f32).
// K half -> Kb[bh][256][64] row-major; V half -> Vt[bh][64][256] transposed
// (scatter 2B stores; moves the transpose off attention's critical path).
// ---------------------------------------------------------------------------
__global__ __launch_bounds__(256) void ln_kernel(
    const float* __restrict__ kvin, const float* __restrict__ gamma,
    const float* __restrict__ beta, ushort* __restrict__ Kb,
    ushort* __restrict__ Vt) {
  const int p = blockIdx.x, tid = threadIdx.x;
  float4 x = reinterpret_cast<const float4*>(kvin + (size_t)p * CDIM)[tid];
  float s = x.x + x.y + x.z + x.w;
  float ss = x.x * x.x + x.y * x.y + x.z * x.z + x.w * x.w;
#pragma unroll
  for (int off = 32; off > 0; off >>= 1) {
    s += __shfl_down(s, off);
    ss += __shfl_down(ss, off);
  }
  __shared__ float sb[4], ssb[4];
  if ((tid & 63) == 0) { sb[tid >> 6] = s; ssb[tid >> 6] = ss; }
  __syncthreads();
  float tot = sb[0] + sb[1] + sb[2] + sb[3];
  float tot2 = ssb[0] + ssb[1] + ssb[2] + ssb[3];
  float mu = tot * (1.f / CDIM);
  float var = tot2 * (1.f / CDIM) - mu * mu;
  float rstd = rsqrtf(var + EPS_);
  float4 g = reinterpret_cast<const float4*>(gamma)[tid];
  float4 bb = reinterpret_cast<const float4*>(beta)[tid];
  ushort o0 = f2b((x.x - mu) * rstd * g.x + bb.x);
  ushort o1 = f2b((x.y - mu) * rstd * g.y + bb.y);
  ushort o2 = f2b((x.z - mu) * rstd * g.z + bb.z);
  ushort o3 = f2b((x.w - mu) * rstd * g.w + bb.w);
  int b = p >> 8, j = p & 255;
  int c = tid * 4;
  if (c < DIM_) {
    int h = c >> 6, d = c & 63;
    ushort4 o = make_ushort4(o0, o1, o2, o3);
    *reinterpret_cast<ushort4*>(&Kb[(((size_t)(b * 8 + h)) * M2 + j) * HD_ + d]) = o;
  } else {
    int c2 = c - DIM_;
    int h = c2 >> 6, d = c2 & 63;
    size_t base = ((size_t)(b * 8 + h) * HD_ + d) * M2 + j;
    Vt[base]           = o0;
    Vt[base + M2]      = o1;
    Vt[base + 2 * M2]  = o2;
    Vt[base + 3 * M2]  = o3;
  }
}

// ---------------------------------------------------------------------------
// MFMA attention. One block per (qt, bh): 4 waves, each 32 q-rows.
// LDS = 64 KiB: K swizzled [256][64] in [0,32K) and V^T swizzled [64][256]
// in [32K,64K), BOTH staged via global_load_lds(16B) with source
// pre-swizzle. After QK^T the K region is dead and is reused for the
// per-wave P buffer (8 KiB each), PV split in two 16-q halves. 2 blocks/CU.
// ---------------------------------------------------------------------------
__global__ __launch_bounds__(256) void attn_mfma_kernel(
    const ushort* __restrict__ qb, const ushort* __restrict__ Kb,
    const ushort* __restrict__ Vt, ushort* __restrict__ attob) {
  __shared__ __align__(16) char lds[65536];
  char* lp = lds;
  const int tid = threadIdx.x;
  const int lane = tid & 63, wid = tid >> 6;
  const int lr = lane & 15, lk = lane >> 4;

  // bh-chunked XCD swizzle: each XCD owns 32 consecutive bh with all 8 qt
  const int l = blockIdx.y * 8 + blockIdx.x;       // 2048 blocks
  const int v = (l & 7) * 256 + (l >> 3);
  const int bh = v >> 3, qt = v & 7;
  const int b = bh >> 3, h = bh & 7;

  auto ks_byte = [](int j, int d) -> int {            // K[256][64]
    return (j << 7) + (((d << 1)) ^ ((j & 7) << 4));
  };
  auto vt_byte = [](int d, int j) -> int {            // V^T[64][256]
    return 32768 + (d << 9) + (((j << 1)) ^ ((d & 7) << 4));
  };
  // P (in dead K region): per-wave 8 KiB, 16 q-rows x 256 kv, bf16
  auto p_byte = [](int w, int q4, int kv) -> int {
    return (w << 13) + (q4 << 9) + (((kv << 1)) ^ ((q4 & 7) << 4));
  };

  const ushort* Khead  = Kb + (size_t)bh * M2 * HD_;   // [256][64]
  const ushort* Vthead = Vt + (size_t)bh * HD_ * M2;   // [64][256]

  // ---- stage K and V^T via global_load_lds, source pre-swizzled ----
#pragma unroll
  for (int it = 0; it < 8; ++it) {
    int o = (it * 256 + tid) * 16;                 // K region byte offset
    int j = o >> 7, c = (o >> 4) & 7;
    int cl = c ^ (j & 7);                          // logical chunk
    __builtin_amdgcn_global_load_lds((gas_t*)(Khead + j * HD_ + cl * 8),
        (las_t*)(lp + o), 16, 0, 0);
  }
#pragma unroll
  for (int it = 0; it < 8; ++it) {
    int o = (it * 256 + tid) * 16;                 // V^T region byte offset
    int d = o >> 9, c = (o >> 4) & 31;
    int cl = c ^ (d & 7);
    __builtin_amdgcn_global_load_lds((gas_t*)(Vthead + d * M2 + cl * 8),
        (las_t*)(lp + 32768 + o), 16, 0, 0);
  }

  const int qbase = qt * 128 + wid * 32;
  bf16x8 qf[2][2];
#pragma unroll
  for (int mf = 0; mf < 2; ++mf)
#pragma unroll
    for (int ks = 0; ks < 2; ++ks)
      qf[mf][ks] = *reinterpret_cast<const bf16x8*>(
          qb + ((size_t)(b * N_ + qbase + mf * 16 + lr)) * DIM_ + h * HD_ + ks * 32 + lk * 8);

  __syncthreads();   // staging complete (drains vmcnt)

  // ---- QK^T: S[32 q][256 kv] ----
  f32x4_t sacc[2][16] = {};
  __builtin_amdgcn_s_setprio(1);
#pragma unroll
  for (int ks = 0; ks < 2; ++ks) {
#pragma unroll
    for (int nj = 0; nj < 16; ++nj) {
      bf16x8 kf = *reinterpret_cast<const bf16x8*>(
          lp + ks_byte(nj * 16 + lr, ks * 32 + lk * 8));
      sacc[0][nj] = __builtin_amdgcn_mfma_f32_16x16x32_bf16(qf[0][ks], kf, sacc[0][nj], 0, 0, 0);
      sacc[1][nj] = __builtin_amdgcn_mfma_f32_16x16x32_bf16(qf[1][ks], kf, sacc[1][nj], 0, 0, 0);
    }
  }
  __builtin_amdgcn_s_setprio(0);

  __syncthreads();   // ALL waves done reading K -> K region reusable for P

  float linv[2][4];
  f32x4_t oacc[2][4] = {};
#pragma unroll
  for (int mf = 0; mf < 2; ++mf) {
    // softmax for this 16-q half (no max-subtraction; alpha ~ N(0,0.016))
#pragma unroll
    for (int r = 0; r < 4; ++r) {
      float pv[16];
      float sum = 0.f;
#pragma unroll
      for (int nj = 0; nj < 16; ++nj) {
        pv[nj] = __expf(sacc[mf][nj][r] * SCALE_);
        sum += pv[nj];
      }
      sum += __shfl_xor(sum, 1);
      sum += __shfl_xor(sum, 2);
      sum += __shfl_xor(sum, 4);
      sum += __shfl_xor(sum, 8);
      linv[mf][r] = 1.f / sum;
      int q4 = lk * 4 + r;
#pragma unroll
      for (int nj = 0; nj < 16; ++nj)
        *reinterpret_cast<ushort*>(lp + p_byte(wid, q4, nj * 16 + lr)) = f2b(pv[nj]);
    }
    // PV for this half (per-wave private P region; in-wave LDS ordering)
    __builtin_amdgcn_s_setprio(1);
#pragma unroll
    for (int ks2 = 0; ks2 < 8; ++ks2) {
      bf16x8 pf = *reinterpret_cast<const bf16x8*>(
          lp + p_byte(wid, lr, ks2 * 32 + lk * 8));
#pragma unroll
      for (int df = 0; df < 4; ++df) {
        bf16x8 vf = *reinterpret_cast<const bf16x8*>(
            lp + vt_byte(df * 16 + lr, ks2 * 32 + lk * 8));
        oacc[mf][df] = __builtin_amdgcn_mfma_f32_16x16x32_bf16(pf, vf, oacc[mf][df], 0, 0, 0);
      }
    }
    __builtin_amdgcn_s_setprio(0);
  }

#pragma unroll
  for (int mf = 0; mf < 2; ++mf)
#pragma unroll
    for (int df = 0; df < 4; ++df)
#pragma unroll
      for (int r = 0; r < 4; ++r) {
        int qrow = qbase + mf * 16 + lk * 4 + r;
        int dcol = df * 16 + lr;
        float val = oacc[mf][df][r] * linv[mf][r];
        attob[((size_t)(b * N_ + qrow)) * DIM_ + h * HD_ + dcol] = f2b(val);
      }
}

// ---------------------------------------------------------------------------
extern "C" void kernel_launch(void* const* d_in, const int* in_sizes, int n_in,
                              void* d_out, int out_size, void* d_ws, size_t ws_size,
                              hipStream_t stream) {
  const float* feats  = (const float*)d_in[0];
  const float* W_q    = (const float*)d_in[1];
  const float* conv_w = (const float*)d_in[2];
  const float* conv_b = (const float*)d_in[3];
  const float* ln_g   = (const float*)d_in[4];
  const float* ln_b   = (const float*)d_in[5];
  const float* W_out  = (const float*)d_in[6];
  float* out = (float*)d_out;

  const size_t FP_ELEMS = (size_t)B_ * PW * PW * DIM_;   // 18.94M
  char* ws = (char*)d_ws;
  ushort* featsp = (ushort*)ws;  ws += FP_ELEMS * 2;                  // 37.9 MB
  ushort* qb     = (ushort*)ws;  ws += (size_t)B_ * N_ * DIM_ * 2;    // 33.5 MB
  ushort* attob  = (ushort*)ws;  ws += (size_t)B_ * N_ * DIM_ * 2;    // 33.5 MB
  float*  kvf    = (float*)ws;   ws += (size_t)B_ * M2 * CDIM * 4;    // 33.5 MB
  ushort* convwb = (ushort*)ws;  ws += (size_t)CDIM * KCONV * 2;      //  9.4 MB
  ushort* wqb    = (ushort*)ws;  ws += (size_t)DIM_ * DIM_ * 2;       //  0.5 MB
  ushort* woutb  = (ushort*)ws;  ws += (size_t)DIM_ * DIM_ * 2;       //  0.5 MB
  ushort* Kb     = (ushort*)ws;  ws += (size_t)B_ * HEAD_ * M2 * HD_ * 2;  // 8.4 MB
  ushort* Vt     = (ushort*)ws;  ws += (size_t)B_ * HEAD_ * M2 * HD_ * 2;  // 8.4 MB

  // padded bf16 feats: zero only the halo border, then fill interior
  zero_border_kernel<<<1056, 256, 0, stream>>>(featsp);
  cast_featsp_kernel<<<16384, 256, 0, stream>>>(feats, featsp);
  cast_f32_bf16_kernel<<<256, 256, 0, stream>>>(W_q, wqb, (DIM_ * DIM_) / 4);
  cast_f32_bf16_kernel<<<256, 256, 0, stream>>>(W_out, woutb, (DIM_ * DIM_) / 4);
  permute_convw_kernel<<<dim3(18, CDIM), 256, 0, stream>>>(conv_w, convwb);

  // q = feats @ W_q^T  -> bf16
  qproj_kernel<<<dim3(DIM_ / 128, (B_ * N_) / 128), 256, 0, stream>>>(
      featsp, wqb, qb);

  // kv_pre = conv(feats) + bias (implicit im2col from padded feats)
  conv_kernel<<<dim3(CDIM / 128, (B_ * M2) / 128), 256, 0, stream>>>(
      featsp, convwb, conv_b, kvf);

  // LayerNorm -> Kb (row-major) + Vt (transposed)
  ln_kernel<<<B_ * M2, 256, 0, stream>>>(kvf, ln_g, ln_b, Kb, Vt);

  // MFMA attention (K + V^T LDS-staged via global_load_lds) -> attob
  attn_mfma_kernel<<<dim3(8, B_ * HEAD_), 256, 0, stream>>>(qb, Kb, Vt, attob);

  // out = attout @ W_out^T
  gemm0_kernel<<<dim3(DIM_ / 128, (B_ * N_) / 128), 256, 0, stream>>>(
      attob, woutb, out, B_ * N_, DIM_, DIM_);
}